// Round 1
// baseline (204.493 us; speedup 1.0000x reference)
//
#include <hip/hip_runtime.h>
#include <hip/hip_bf16.h>
#include <math.h>

// Problem constants
#define BB   2
#define LL   2048
#define DD   512
#define KK   32
#define BL   (BB*LL)      // 4096
#define NCH  64           // chunks along L
#define LC   (LL/NCH)     // 32 rows per chunk

// ---------------------------------------------------------------------------
// Generic fp32 tiled GEMM: out[M,N] = epi(A[M,K] @ W[K,N] + bias [+ resid])
// 64x64 tile, 16x16 threads, 4x4 micro-tile, BK=16.
// epi: 0 = plain+bias, 1 = tanh(.+bias), 2 = resid + . + bias
// ---------------------------------------------------------------------------
__global__ __launch_bounds__(256) void gemm64(const float* __restrict__ A,
                                              const float* __restrict__ W,
                                              const float* __restrict__ bias,
                                              const float* __restrict__ resid,
                                              float* __restrict__ out,
                                              int M, int N, int Kd, int epi)
{
    __shared__ float As[16][68];   // transposed A tile [k][m], padded
    __shared__ float Ws[16][64];   // W tile [k][n]

    const int t  = threadIdx.x;
    const int m0 = blockIdx.y * 64;
    const int n0 = blockIdx.x * 64;
    const int ty = t >> 4, tx = t & 15;
    const int ar = t >> 2, ac4 = t & 3;    // A loader: row 0..63, col4 0..3
    const int wr = t >> 4, wc4 = t & 15;   // W loader: row 0..15, col4 0..15

    float acc[4][4] = {};

    for (int k0 = 0; k0 < Kd; k0 += 16) {
        float4 av = *(const float4*)(A + (size_t)(m0 + ar) * Kd + k0 + ac4 * 4);
        float4 wv = *(const float4*)(W + (size_t)(k0 + wr) * N + n0 + wc4 * 4);
        __syncthreads();
        As[ac4*4+0][ar] = av.x;
        As[ac4*4+1][ar] = av.y;
        As[ac4*4+2][ar] = av.z;
        As[ac4*4+3][ar] = av.w;
        *(float4*)&Ws[wr][wc4*4] = wv;
        __syncthreads();
        #pragma unroll
        for (int k = 0; k < 16; ++k) {
            float4 a = *(const float4*)&As[k][ty*4];
            float4 w = *(const float4*)&Ws[k][tx*4];
            acc[0][0] = fmaf(a.x, w.x, acc[0][0]);
            acc[0][1] = fmaf(a.x, w.y, acc[0][1]);
            acc[0][2] = fmaf(a.x, w.z, acc[0][2]);
            acc[0][3] = fmaf(a.x, w.w, acc[0][3]);
            acc[1][0] = fmaf(a.y, w.x, acc[1][0]);
            acc[1][1] = fmaf(a.y, w.y, acc[1][1]);
            acc[1][2] = fmaf(a.y, w.z, acc[1][2]);
            acc[1][3] = fmaf(a.y, w.w, acc[1][3]);
            acc[2][0] = fmaf(a.z, w.x, acc[2][0]);
            acc[2][1] = fmaf(a.z, w.y, acc[2][1]);
            acc[2][2] = fmaf(a.z, w.z, acc[2][2]);
            acc[2][3] = fmaf(a.z, w.w, acc[2][3]);
            acc[3][0] = fmaf(a.w, w.x, acc[3][0]);
            acc[3][1] = fmaf(a.w, w.y, acc[3][1]);
            acc[3][2] = fmaf(a.w, w.z, acc[3][2]);
            acc[3][3] = fmaf(a.w, w.w, acc[3][3]);
        }
    }

    #pragma unroll
    for (int i = 0; i < 4; ++i) {
        int row = m0 + ty*4 + i;
        #pragma unroll
        for (int j = 0; j < 4; ++j) {
            int col = n0 + tx*4 + j;
            float v = acc[i][j] + bias[col];
            if (epi == 1) v = tanhf(v);
            else if (epi == 2) v += resid[(size_t)row * N + col];
            out[(size_t)row * N + col] = v;
        }
    }
}

// ---------------------------------------------------------------------------
// Phase kernel: per row, 32-wide GEMM vs W2, then phases -> cos/sin tables.
// Block: 256 threads = 8 rows x 32 k.
// ---------------------------------------------------------------------------
__global__ __launch_bounds__(256) void phase_kernel(const float* __restrict__ H,
                                                    const float* __restrict__ W2,
                                                    const float* __restrict__ b2,
                                                    const float* __restrict__ ps_p,
                                                    const float* __restrict__ cs_p,
                                                    float* __restrict__ Ca,
                                                    float* __restrict__ Sa)
{
    __shared__ float Hs[8][DD];
    const int t  = threadIdx.x;
    const int rl = t >> 5;      // local row 0..7
    const int j  = t & 31;      // k index
    const int row0 = blockIdx.x * 8;

    // cooperative load of 8 rows (4096 floats) as float4
    const float4* src = (const float4*)(H + (size_t)row0 * DD);
    float4* dst = (float4*)Hs;
    #pragma unroll
    for (int i = 0; i < 4; ++i) dst[t + i*256] = src[t + i*256];
    __syncthreads();

    float dot = 0.f;
    #pragma unroll 8
    for (int d = 0; d < DD; ++d)
        dot = fmaf(Hs[rl][d], W2[d*KK + j], dot);

    const float ps = ps_p[0];
    const float cs = cs_p[0];
    const int gr = row0 + rl;          // global row 0..4095
    const int l  = gr & (LL - 1);      // position within batch
    // freq = 10000^(-j/K)  == exp2(-j * log2(10000)/K)
    const float freq = exp2f(-(float)j * (13.287712379549449f / (float)KK));
    const float content = tanhf(dot + b2[j]) * 3.14159265358979323846f * cs;
    const float total = ps * ((float)l * freq) + content;
    float sv, cv;
    sincosf(total, &sv, &cv);
    Ca[(size_t)gr * KK + j] = cv;
    Sa[(size_t)gr * KK + j] = sv;
}

// ---------------------------------------------------------------------------
// Scan pass A: per-(b,chunk,d) local sums of c*v and s*v over the chunk.
// grid (B*NCH, D/256), block 256. Writes PR/PI [b][ch][k][d].
// ---------------------------------------------------------------------------
__global__ __launch_bounds__(256) void scan_partial(const float* __restrict__ Ca,
                                                    const float* __restrict__ Sa,
                                                    const float* __restrict__ V,
                                                    float* __restrict__ PR,
                                                    float* __restrict__ PI_)
{
    __shared__ float Cs[LC*KK];
    __shared__ float Ss[LC*KK];
    const int t = threadIdx.x;
    const int bch = blockIdx.x;         // b*NCH + ch
    const int d = blockIdx.y * 256 + t;
    const int b = bch >> 6;
    const int ch = bch & (NCH - 1);

    const size_t pbase_in = ((size_t)b * LL + (size_t)ch * LC) * KK;
    ((float4*)Cs)[t] = ((const float4*)(Ca + pbase_in))[t];   // LC*KK=1024 floats
    ((float4*)Ss)[t] = ((const float4*)(Sa + pbase_in))[t];
    __syncthreads();

    float mr[KK] = {}, mi[KK] = {};
    const float* vp = V + ((size_t)b * LL + (size_t)ch * LC) * DD + d;
    for (int l = 0; l < LC; ++l) {
        float v = vp[(size_t)l * DD];
        #pragma unroll
        for (int k = 0; k < KK; ++k) {
            mr[k] = fmaf(Cs[l*KK + k], v, mr[k]);
            mi[k] = fmaf(Ss[l*KK + k], v, mi[k]);
        }
    }
    const size_t pbase = (size_t)bch * KK * DD + d;
    #pragma unroll
    for (int k = 0; k < KK; ++k) {
        PR[pbase + (size_t)k * DD] = mr[k];
        PI_[pbase + (size_t)k * DD] = mi[k];
    }
}

// ---------------------------------------------------------------------------
// Scan pass B: in-place exclusive prefix over the 64 chunks, per (b,k,d).
// ---------------------------------------------------------------------------
__global__ __launch_bounds__(256) void scan_prefix(float* __restrict__ PR,
                                                   float* __restrict__ PI_)
{
    const int g = blockIdx.x * 256 + threadIdx.x;   // 0 .. B*K*D-1
    const int b = g >> 14;                          // K*D = 16384
    const int kd = g & 16383;
    float r = 0.f, ri = 0.f;
    for (int ch = 0; ch < NCH; ++ch) {
        size_t idx = ((size_t)(b * NCH + ch)) * (KK * DD) + kd;
        float t0 = PR[idx];  PR[idx] = r;  r += t0;
        float t1 = PI_[idx]; PI_[idx] = ri; ri += t1;
    }
}

// ---------------------------------------------------------------------------
// Scan pass C: replay chunk with exclusive-prefix init, fuse retrieve + norm.
// ---------------------------------------------------------------------------
__global__ __launch_bounds__(256) void scan_retrieve(const float* __restrict__ Ca,
                                                     const float* __restrict__ Sa,
                                                     const float* __restrict__ V,
                                                     const float* __restrict__ PR,
                                                     const float* __restrict__ PI_,
                                                     float* __restrict__ RET)
{
    __shared__ float Cs[LC*KK];
    __shared__ float Ss[LC*KK];
    const int t = threadIdx.x;
    const int bch = blockIdx.x;
    const int d = blockIdx.y * 256 + t;
    const int b = bch >> 6;
    const int ch = bch & (NCH - 1);

    const size_t pbase_in = ((size_t)b * LL + (size_t)ch * LC) * KK;
    ((float4*)Cs)[t] = ((const float4*)(Ca + pbase_in))[t];
    ((float4*)Ss)[t] = ((const float4*)(Sa + pbase_in))[t];
    __syncthreads();

    float mr[KK], mi[KK];
    const size_t pbase = (size_t)bch * KK * DD + d;
    #pragma unroll
    for (int k = 0; k < KK; ++k) {
        mr[k] = PR[pbase + (size_t)k * DD];
        mi[k] = PI_[pbase + (size_t)k * DD];
    }

    const float* vp = V + ((size_t)b * LL + (size_t)ch * LC) * DD + d;
    float* rp = RET + ((size_t)b * LL + (size_t)ch * LC) * DD + d;
    for (int l = 0; l < LC; ++l) {
        float v = vp[(size_t)l * DD];
        float ret = 0.f;
        #pragma unroll
        for (int k = 0; k < KK; ++k) {
            float c = Cs[l*KK + k], s = Ss[l*KK + k];
            mr[k] = fmaf(c, v, mr[k]);
            ret   = fmaf(c, mr[k], ret);
            mi[k] = fmaf(s, v, mi[k]);
            ret   = fmaf(s, mi[k], ret);
        }
        int gl = ch * LC + l;
        rp[(size_t)l * DD] = ret * rsqrtf((float)((gl + 1) * KK));
    }
}

// ---------------------------------------------------------------------------
// LayerNorm over D=512 per row. Block 256, each thread handles 2 elements.
// ---------------------------------------------------------------------------
__global__ __launch_bounds__(256) void ln_kernel(const float* __restrict__ RET,
                                                 const float* __restrict__ g,
                                                 const float* __restrict__ be,
                                                 float* __restrict__ LN)
{
    const int row = blockIdx.x;
    const int t = threadIdx.x;
    const float* r = RET + (size_t)row * DD;
    float a = r[t], b = r[t + 256];
    float s = a + b, sq = fmaf(a, a, b * b);
    #pragma unroll
    for (int off = 32; off > 0; off >>= 1) {
        s  += __shfl_down(s, off);
        sq += __shfl_down(sq, off);
    }
    __shared__ float ls[4], lq[4];
    const int wid = t >> 6, lane = t & 63;
    if (lane == 0) { ls[wid] = s; lq[wid] = sq; }
    __syncthreads();
    if (t == 0) {
        ls[0] = ls[0] + ls[1] + ls[2] + ls[3];
        lq[0] = lq[0] + lq[1] + lq[2] + lq[3];
    }
    __syncthreads();
    const float mu  = ls[0] * (1.0f / DD);
    const float var = lq[0] * (1.0f / DD) - mu * mu;
    const float rstd = rsqrtf(var + 1e-5f);
    LN[(size_t)row * DD + t]       = (a - mu) * rstd * g[t] + be[t];
    LN[(size_t)row * DD + t + 256] = (b - mu) * rstd * g[t + 256] + be[t + 256];
}

// ---------------------------------------------------------------------------
extern "C" void kernel_launch(void* const* d_in, const int* in_sizes, int n_in,
                              void* d_out, int out_size, void* d_ws, size_t ws_size,
                              hipStream_t stream)
{
    const float* x   = (const float*)d_in[0];
    const float* W1  = (const float*)d_in[1];
    const float* b1  = (const float*)d_in[2];
    const float* W2  = (const float*)d_in[3];
    const float* b2  = (const float*)d_in[4];
    const float* ps  = (const float*)d_in[5];
    const float* cs  = (const float*)d_in[6];
    const float* Wv  = (const float*)d_in[7];
    const float* bv  = (const float*)d_in[8];
    const float* lng = (const float*)d_in[9];
    const float* lnb = (const float*)d_in[10];
    const float* Wo  = (const float*)d_in[11];
    const float* bo  = (const float*)d_in[12];
    float* out = (float*)d_out;

    float* w = (float*)d_ws;
    float* H  = w;                       // 2M floats (reused as RET)
    float* V  = w + 2097152;             // 2M floats (reused as LN)
    float* Ca = w + 4194304;             // 128K
    float* Sa = w + 4325376;             // 128K
    float* PR = w + 4456448;             // 2M
    float* PI_ = w + 6553600;            // 2M

    dim3 gb(DD / 64, BL / 64);           // (8, 64)
    dim3 bb(256);

    // 1. H = tanh(x@W1 + b1)
    gemm64<<<gb, bb, 0, stream>>>(x, W1, b1, nullptr, H, BL, DD, DD, 1);
    // 2. phases -> C,S
    phase_kernel<<<dim3(BL / 8), bb, 0, stream>>>(H, W2, b2, ps, cs, Ca, Sa);
    // 3. V = x@Wv + bv
    gemm64<<<gb, bb, 0, stream>>>(x, Wv, bv, nullptr, V, BL, DD, DD, 0);
    // 4-6. chunked scan
    scan_partial<<<dim3(BB * NCH, DD / 256), bb, 0, stream>>>(Ca, Sa, V, PR, PI_);
    scan_prefix<<<dim3((BB * KK * DD) / 256), bb, 0, stream>>>(PR, PI_);
    scan_retrieve<<<dim3(BB * NCH, DD / 256), bb, 0, stream>>>(Ca, Sa, V, PR, PI_, H);
    // 7. LayerNorm (RET lives in H; LN into V)
    ln_kernel<<<dim3(BL), bb, 0, stream>>>(H, lng, lnb, V);
    // 8. out = x + LN@Wo + bo
    gemm64<<<gb, bb, 0, stream>>>(V, Wo, bo, x, out, BL, DD, DD, 2);
}

// Round 2
// 120.991 us; speedup vs baseline: 1.6902x; 1.6902x over previous
//
#include <hip/hip_runtime.h>
#include <hip/hip_bf16.h>
#include <math.h>

// Problem constants
#define BB   2
#define LL   2048
#define DD   512
#define KK   32
#define BL   (BB*LL)      // 4096
#define NCH  64           // chunks along L
#define LC   (LL/NCH)     // 32 rows per chunk

typedef unsigned short ushort_t;
typedef __bf16 bf16x8 __attribute__((ext_vector_type(8)));
typedef float  f32x4  __attribute__((ext_vector_type(4)));

__device__ __forceinline__ void gl_lds16(const void* g, void* l) {
    __builtin_amdgcn_global_load_lds(
        (const __attribute__((address_space(1))) void*)g,
        (__attribute__((address_space(3))) void*)l, 16, 0, 0);
}

// ---------------------------------------------------------------------------
// cast fp32 -> bf16, 4 elems/thread
// ---------------------------------------------------------------------------
__global__ __launch_bounds__(256) void cast_bf16(const float* __restrict__ in,
                                                 __hip_bfloat16* __restrict__ out)
{
    const int i = (blockIdx.x * 256 + threadIdx.x) * 4;
    float4 v = *(const float4*)(in + i);
    __hip_bfloat16 o[4] = {__float2bfloat16(v.x), __float2bfloat16(v.y),
                           __float2bfloat16(v.z), __float2bfloat16(v.w)};
    *(ushort4*)(out + i) = *(const ushort4*)o;
}

// ---------------------------------------------------------------------------
// transpose + cast weights: dst[n][k] = src[k][n], 512x512, bf16 out.
// z: 0=W1->Wct[0:512], 1=Wv->Wct[512:1024], 2=Wo->Wot
// ---------------------------------------------------------------------------
__global__ void transpose_w(const float* __restrict__ W1,
                            const float* __restrict__ Wv,
                            const float* __restrict__ Wo,
                            __hip_bfloat16* __restrict__ Wct,
                            __hip_bfloat16* __restrict__ Wot)
{
    __shared__ float tile[32][33];
    const float* src = blockIdx.z == 0 ? W1 : (blockIdx.z == 1 ? Wv : Wo);
    __hip_bfloat16* dst = blockIdx.z == 0 ? Wct
                        : (blockIdx.z == 1 ? Wct + 512 * 512 : Wot);
    const int r0 = blockIdx.y * 32, c0 = blockIdx.x * 32;
    const int tx = threadIdx.x, ty = threadIdx.y;
    #pragma unroll
    for (int i = 0; i < 4; ++i)
        tile[ty + 8 * i][tx] = src[(size_t)(r0 + ty + 8 * i) * 512 + c0 + tx];
    __syncthreads();
    #pragma unroll
    for (int i = 0; i < 4; ++i)
        dst[(size_t)(c0 + ty + 8 * i) * 512 + r0 + tx] =
            __float2bfloat16(tile[tx][ty + 8 * i]);
}

// ---------------------------------------------------------------------------
// bf16 MFMA GEMM: C[M,N] = A[M,512] @ Bt[N,512]^T (+bias, epilogue per MODE)
// BM x 128 tile, 256 threads = 4 waves (2x2), 16x16x32 MFMA, BK=64.
// LDS layout: [row][slot^(row&7)] of 16B slots (8 slots/row of 128B) ->
// conflict-free ds_read_b128; staged via global_load_lds with pre-swizzled
// global source (m173 pattern).
// MODE 0: cols<512 -> outH = bf16(tanh(.+bias0)); cols>=512 -> outV = bf16(.+bias1)
// MODE 1: outF = . + bias0 + resid
// ---------------------------------------------------------------------------
template<int BM, int MODE>
__global__ __launch_bounds__(256) void gemm_mfma(
    const ushort_t* __restrict__ A, const ushort_t* __restrict__ Bt,
    const float* __restrict__ bias0, const float* __restrict__ bias1,
    const float* __restrict__ resid,
    __hip_bfloat16* __restrict__ outH, __hip_bfloat16* __restrict__ outV,
    float* __restrict__ outF)
{
    constexpr int WROWS = BM / 2;      // rows per wave
    constexpr int MF    = WROWS / 16;  // m-fragments per wave
    constexpr int ACH   = BM / 32;     // A staging chunks per thread
    __shared__ __align__(16) ushort_t As[BM * 64];
    __shared__ __align__(16) ushort_t Bs[128 * 64];

    const int t  = threadIdx.x;
    const int m0 = blockIdx.y * BM, n0 = blockIdx.x * 128;
    const int l  = t & 63, w = t >> 6;
    const int wr = w >> 1, wc = w & 1;
    const int l15 = l & 15, hi = l >> 4;

    // staging: linear LDS dest (chunk i*256+t), global source pre-swizzled
    const ushort_t* agp[ACH];
    const ushort_t* bgp[4];
    #pragma unroll
    for (int i = 0; i < ACH; ++i) {
        int row = (t >> 3) + 32 * i, slot = (t & 7) ^ (row & 7);
        agp[i] = A + (size_t)(m0 + row) * 512 + slot * 8;
    }
    #pragma unroll
    for (int i = 0; i < 4; ++i) {
        int row = (t >> 3) + 32 * i, slot = (t & 7) ^ (row & 7);
        bgp[i] = Bt + (size_t)(n0 + row) * 512 + slot * 8;
    }

    // LDS fragment read byte-addresses (loop-invariant)
    int aoff[MF][2], boff[4][2];
    #pragma unroll
    for (int mi = 0; mi < MF; ++mi)
        #pragma unroll
        for (int kh = 0; kh < 2; ++kh) {
            int row = wr * WROWS + mi * 16 + l15;
            aoff[mi][kh] = row * 128 + (((kh * 4 + hi) ^ (row & 7)) * 16);
        }
    #pragma unroll
    for (int nj = 0; nj < 4; ++nj)
        #pragma unroll
        for (int kh = 0; kh < 2; ++kh) {
            int row = wc * 64 + nj * 16 + l15;
            boff[nj][kh] = row * 128 + (((kh * 4 + hi) ^ (row & 7)) * 16);
        }

    f32x4 acc[MF][4];
    #pragma unroll
    for (int mi = 0; mi < MF; ++mi)
        #pragma unroll
        for (int nj = 0; nj < 4; ++nj)
            acc[mi][nj] = f32x4{0.f, 0.f, 0.f, 0.f};

    for (int k0 = 0; k0 < 512; k0 += 64) {
        __syncthreads();
        #pragma unroll
        for (int i = 0; i < ACH; ++i)
            gl_lds16(agp[i] + k0, (char*)As + (size_t)(i * 256 + t) * 16);
        #pragma unroll
        for (int i = 0; i < 4; ++i)
            gl_lds16(bgp[i] + k0, (char*)Bs + (size_t)(i * 256 + t) * 16);
        __syncthreads();
        #pragma unroll
        for (int kh = 0; kh < 2; ++kh) {
            bf16x8 af[MF], bfr[4];
            #pragma unroll
            for (int mi = 0; mi < MF; ++mi)
                af[mi] = *(const bf16x8*)((const char*)As + aoff[mi][kh]);
            #pragma unroll
            for (int nj = 0; nj < 4; ++nj)
                bfr[nj] = *(const bf16x8*)((const char*)Bs + boff[nj][kh]);
            #pragma unroll
            for (int mi = 0; mi < MF; ++mi)
                #pragma unroll
                for (int nj = 0; nj < 4; ++nj)
                    acc[mi][nj] = __builtin_amdgcn_mfma_f32_16x16x32_bf16(
                        af[mi], bfr[nj], acc[mi][nj], 0, 0, 0);
        }
    }

    // epilogue: D layout col=lane&15, row=(lane>>4)*4+reg
    #pragma unroll
    for (int nj = 0; nj < 4; ++nj) {
        const int gcol = n0 + wc * 64 + nj * 16 + l15;
        float bsv;
        if (MODE == 0) bsv = (gcol < 512) ? bias0[gcol] : bias1[gcol - 512];
        else           bsv = bias0[gcol];
        #pragma unroll
        for (int mi = 0; mi < MF; ++mi) {
            #pragma unroll
            for (int r = 0; r < 4; ++r) {
                const int grow = m0 + wr * WROWS + mi * 16 + hi * 4 + r;
                float v = acc[mi][nj][r] + bsv;
                if (MODE == 0) {
                    if (gcol < 512)
                        outH[(size_t)grow * 512 + gcol] = __float2bfloat16(tanhf(v));
                    else
                        outV[(size_t)grow * 512 + (gcol - 512)] = __float2bfloat16(v);
                } else {
                    outF[(size_t)grow * 512 + gcol] =
                        v + resid[(size_t)grow * 512 + gcol];
                }
            }
        }
    }
}

// ---------------------------------------------------------------------------
// Phase kernel: per row, 32-wide dot vs W2, then phases -> cos/sin tables.
// Block: 256 threads = 8 rows x 32 k. H is bf16.
// ---------------------------------------------------------------------------
__global__ __launch_bounds__(256) void phase_kernel(const __hip_bfloat16* __restrict__ H,
                                                    const float* __restrict__ W2,
                                                    const float* __restrict__ b2,
                                                    const float* __restrict__ ps_p,
                                                    const float* __restrict__ cs_p,
                                                    float* __restrict__ Ca,
                                                    float* __restrict__ Sa)
{
    __shared__ __align__(16) __hip_bfloat16 Hs[8 * DD];
    const int t  = threadIdx.x;
    const int rl = t >> 5;      // local row 0..7
    const int j  = t & 31;      // k index
    const int row0 = blockIdx.x * 8;

    const float4* src = (const float4*)(H + (size_t)row0 * DD);  // 512 float4
    float4* dst = (float4*)Hs;
    dst[t] = src[t];
    dst[t + 256] = src[t + 256];
    __syncthreads();

    float dot = 0.f;
    #pragma unroll 8
    for (int d = 0; d < DD; ++d)
        dot = fmaf(__bfloat162float(Hs[rl * DD + d]), W2[d * KK + j], dot);

    const float ps = ps_p[0];
    const float cs = cs_p[0];
    const int gr = row0 + rl;
    const int lpos = gr & (LL - 1);
    const float freq = exp2f(-(float)j * (13.287712379549449f / (float)KK));
    const float content = tanhf(dot + b2[j]) * 3.14159265358979323846f * cs;
    const float total = ps * ((float)lpos * freq) + content;
    float sv, cv;
    sincosf(total, &sv, &cv);
    Ca[(size_t)gr * KK + j] = cv;
    Sa[(size_t)gr * KK + j] = sv;
}

// ---------------------------------------------------------------------------
// Scan pass A: per-(b,chunk,d) local sums of c*v and s*v over the chunk.
// ---------------------------------------------------------------------------
__global__ __launch_bounds__(256) void scan_partial(const float* __restrict__ Ca,
                                                    const float* __restrict__ Sa,
                                                    const __hip_bfloat16* __restrict__ V,
                                                    float* __restrict__ PR,
                                                    float* __restrict__ PI_)
{
    __shared__ __align__(16) float Cs[LC * KK];
    __shared__ __align__(16) float Ss[LC * KK];
    const int t = threadIdx.x;
    const int bch = blockIdx.x;
    const int d = blockIdx.y * 256 + t;
    const int b = bch >> 6;
    const int ch = bch & (NCH - 1);

    const size_t pbase_in = ((size_t)b * LL + (size_t)ch * LC) * KK;
    ((float4*)Cs)[t] = ((const float4*)(Ca + pbase_in))[t];
    ((float4*)Ss)[t] = ((const float4*)(Sa + pbase_in))[t];
    __syncthreads();

    float mr[KK] = {}, mi[KK] = {};
    const __hip_bfloat16* vp = V + ((size_t)b * LL + (size_t)ch * LC) * DD + d;
    for (int lrow = 0; lrow < LC; ++lrow) {
        float v = __bfloat162float(vp[(size_t)lrow * DD]);
        #pragma unroll
        for (int k4 = 0; k4 < KK / 4; ++k4) {
            float4 c = *(const float4*)&Cs[lrow * KK + k4 * 4];
            float4 s = *(const float4*)&Ss[lrow * KK + k4 * 4];
            mr[k4*4+0] = fmaf(c.x, v, mr[k4*4+0]);
            mr[k4*4+1] = fmaf(c.y, v, mr[k4*4+1]);
            mr[k4*4+2] = fmaf(c.z, v, mr[k4*4+2]);
            mr[k4*4+3] = fmaf(c.w, v, mr[k4*4+3]);
            mi[k4*4+0] = fmaf(s.x, v, mi[k4*4+0]);
            mi[k4*4+1] = fmaf(s.y, v, mi[k4*4+1]);
            mi[k4*4+2] = fmaf(s.z, v, mi[k4*4+2]);
            mi[k4*4+3] = fmaf(s.w, v, mi[k4*4+3]);
        }
    }
    const size_t pbase = (size_t)bch * KK * DD + d;
    #pragma unroll
    for (int k = 0; k < KK; ++k) {
        PR[pbase + (size_t)k * DD]  = mr[k];
        PI_[pbase + (size_t)k * DD] = mi[k];
    }
}

// ---------------------------------------------------------------------------
// Scan pass B: in-place exclusive prefix over the 64 chunks, per (b,k,d).
// ---------------------------------------------------------------------------
__global__ __launch_bounds__(256) void scan_prefix(float* __restrict__ PR,
                                                   float* __restrict__ PI_)
{
    const int g = blockIdx.x * 256 + threadIdx.x;
    const int b = g >> 14;                          // K*D = 16384
    const int kd = g & 16383;
    float r = 0.f, ri = 0.f;
    for (int ch = 0; ch < NCH; ++ch) {
        size_t idx = ((size_t)(b * NCH + ch)) * (KK * DD) + kd;
        float t0 = PR[idx];  PR[idx] = r;  r += t0;
        float t1 = PI_[idx]; PI_[idx] = ri; ri += t1;
    }
}

// ---------------------------------------------------------------------------
// Scan pass C: replay chunk with exclusive-prefix init, fuse retrieve + norm.
// RET aliases V (in-place, element read-then-write per l).
// ---------------------------------------------------------------------------
__global__ __launch_bounds__(256) void scan_retrieve(const float* __restrict__ Ca,
                                                     const float* __restrict__ Sa,
                                                     __hip_bfloat16* V,
                                                     const float* __restrict__ PR,
                                                     const float* __restrict__ PI_)
{
    __shared__ __align__(16) float Cs[LC * KK];
    __shared__ __align__(16) float Ss[LC * KK];
    const int t = threadIdx.x;
    const int bch = blockIdx.x;
    const int d = blockIdx.y * 256 + t;
    const int b = bch >> 6;
    const int ch = bch & (NCH - 1);

    const size_t pbase_in = ((size_t)b * LL + (size_t)ch * LC) * KK;
    ((float4*)Cs)[t] = ((const float4*)(Ca + pbase_in))[t];
    ((float4*)Ss)[t] = ((const float4*)(Sa + pbase_in))[t];
    __syncthreads();

    float mr[KK], mi[KK];
    const size_t pbase = (size_t)bch * KK * DD + d;
    #pragma unroll
    for (int k = 0; k < KK; ++k) {
        mr[k] = PR[pbase + (size_t)k * DD];
        mi[k] = PI_[pbase + (size_t)k * DD];
    }

    __hip_bfloat16* vp = V + ((size_t)b * LL + (size_t)ch * LC) * DD + d;
    for (int lrow = 0; lrow < LC; ++lrow) {
        float v = __bfloat162float(vp[(size_t)lrow * DD]);
        float ret = 0.f;
        #pragma unroll
        for (int k = 0; k < KK; ++k) {
            float c = Cs[lrow * KK + k], s = Ss[lrow * KK + k];
            mr[k] = fmaf(c, v, mr[k]);
            ret   = fmaf(c, mr[k], ret);
            mi[k] = fmaf(s, v, mi[k]);
            ret   = fmaf(s, mi[k], ret);
        }
        int gl = ch * LC + lrow;
        vp[(size_t)lrow * DD] =
            __float2bfloat16(ret * rsqrtf((float)((gl + 1) * KK)));
    }
}

// ---------------------------------------------------------------------------
// LayerNorm over D=512 per row; bf16 in, bf16 out.
// ---------------------------------------------------------------------------
__global__ __launch_bounds__(256) void ln_kernel(const __hip_bfloat16* __restrict__ RET,
                                                 const float* __restrict__ g,
                                                 const float* __restrict__ be,
                                                 __hip_bfloat16* __restrict__ LN)
{
    const int row = blockIdx.x;
    const int t = threadIdx.x;
    const __hip_bfloat16* r = RET + (size_t)row * DD;
    float a = __bfloat162float(r[t]), b = __bfloat162float(r[t + 256]);
    float s = a + b, sq = fmaf(a, a, b * b);
    #pragma unroll
    for (int off = 32; off > 0; off >>= 1) {
        s  += __shfl_down(s, off);
        sq += __shfl_down(sq, off);
    }
    __shared__ float ls[4], lq[4];
    const int wid = t >> 6, lane = t & 63;
    if (lane == 0) { ls[wid] = s; lq[wid] = sq; }
    __syncthreads();
    if (t == 0) {
        ls[0] = ls[0] + ls[1] + ls[2] + ls[3];
        lq[0] = lq[0] + lq[1] + lq[2] + lq[3];
    }
    __syncthreads();
    const float mu  = ls[0] * (1.0f / DD);
    const float var = lq[0] * (1.0f / DD) - mu * mu;
    const float rstd = rsqrtf(var + 1e-5f);
    LN[(size_t)row * DD + t] =
        __float2bfloat16((a - mu) * rstd * g[t] + be[t]);
    LN[(size_t)row * DD + t + 256] =
        __float2bfloat16((b - mu) * rstd * g[t + 256] + be[t + 256]);
}

// ---------------------------------------------------------------------------
extern "C" void kernel_launch(void* const* d_in, const int* in_sizes, int n_in,
                              void* d_out, int out_size, void* d_ws, size_t ws_size,
                              hipStream_t stream)
{
    const float* x   = (const float*)d_in[0];
    const float* W1  = (const float*)d_in[1];
    const float* b1  = (const float*)d_in[2];
    const float* W2  = (const float*)d_in[3];
    const float* b2  = (const float*)d_in[4];
    const float* ps  = (const float*)d_in[5];
    const float* cs  = (const float*)d_in[6];
    const float* Wv  = (const float*)d_in[7];
    const float* bv  = (const float*)d_in[8];
    const float* lng = (const float*)d_in[9];
    const float* lnb = (const float*)d_in[10];
    const float* Wo  = (const float*)d_in[11];
    const float* bo  = (const float*)d_in[12];
    float* out = (float*)d_out;

    char* wsb = (char*)d_ws;
    __hip_bfloat16* Vb  = (__hip_bfloat16*)(wsb);                       // 4 MB
    float* PR  = (float*)(wsb + (4u  << 20));                           // 8 MB
    float* PI_ = (float*)(wsb + (12u << 20));                           // 8 MB
    float* Ca  = (float*)(wsb + (20u << 20));                           // 512 KB
    float* Sa  = (float*)(wsb + (20u << 20) + (512u << 10));            // 512 KB
    __hip_bfloat16* xb  = (__hip_bfloat16*)(wsb + (21u << 20));         // 4 MB
    __hip_bfloat16* Hb  = (__hip_bfloat16*)(wsb + (25u << 20));         // 4 MB (also LNb)
    __hip_bfloat16* Wct = (__hip_bfloat16*)(wsb + (29u << 20));         // 1 MB
    __hip_bfloat16* Wot = (__hip_bfloat16*)(wsb + (30u << 20));         // 0.5 MB

    // 0. casts / transposes
    cast_bf16<<<dim3(BL * DD / 1024), dim3(256), 0, stream>>>(x, xb);
    transpose_w<<<dim3(16, 16, 3), dim3(32, 8), 0, stream>>>(W1, Wv, Wo, Wct, Wot);
    // 1+3 fused: [H|V] = x @ [W1|Wv] with tanh / +bias epilogues
    gemm_mfma<64, 0><<<dim3(8, BL / 64), dim3(256), 0, stream>>>(
        (const ushort_t*)xb, (const ushort_t*)Wct, b1, bv, nullptr, Hb, Vb, nullptr);
    // 2. phases -> C,S
    phase_kernel<<<dim3(BL / 8), dim3(256), 0, stream>>>(Hb, W2, b2, ps, cs, Ca, Sa);
    // 4-6. chunked scan (RET in-place over Vb)
    scan_partial<<<dim3(BB * NCH, DD / 256), dim3(256), 0, stream>>>(Ca, Sa, Vb, PR, PI_);
    scan_prefix<<<dim3((BB * KK * DD) / 256), dim3(256), 0, stream>>>(PR, PI_);
    scan_retrieve<<<dim3(BB * NCH, DD / 256), dim3(256), 0, stream>>>(Ca, Sa, Vb, PR, PI_);
    // 7. LayerNorm (RET in Vb -> LNb in Hb)
    ln_kernel<<<dim3(BL), dim3(256), 0, stream>>>(Vb, lng, lnb, Hb);
    // 8. out = x + LN @ Wo + bo
    gemm_mfma<64, 1><<<dim3(4, BL / 64), dim3(256), 0, stream>>>(
        (const ushort_t*)Hb, (const ushort_t*)Wot, bo, nullptr, x, nullptr, nullptr, out);
}

// Round 3
// 91.248 us; speedup vs baseline: 2.2411x; 1.3260x over previous
//
#include <hip/hip_runtime.h>
#include <hip/hip_bf16.h>
#include <math.h>

// Problem constants
#define BB   2
#define LL   2048
#define DD   512
#define KK   32
#define BL   (BB*LL)      // 4096
#define NCH  64           // chunks along L
#define LC   32           // rows per chunk

typedef unsigned short ushort_t;
typedef __bf16 bf16x8 __attribute__((ext_vector_type(8)));
typedef float  f32x4  __attribute__((ext_vector_type(4)));
typedef unsigned short ushort8 __attribute__((ext_vector_type(8)));

__device__ __forceinline__ void gl_lds16(const void* g, void* l) {
    __builtin_amdgcn_global_load_lds(
        (const __attribute__((address_space(1))) void*)g,
        (__attribute__((address_space(3))) void*)l, 16, 0, 0);
}
__device__ __forceinline__ ushort_t f2b(float f) {
    __bf16 b = (__bf16)f; return *(ushort_t*)&b;
}

// ---------------------------------------------------------------------------
// cast fp32 -> bf16, 4 elems/thread
// ---------------------------------------------------------------------------
__global__ __launch_bounds__(256) void cast_bf16(const float* __restrict__ in,
                                                 __hip_bfloat16* __restrict__ out)
{
    const int i = (blockIdx.x * 256 + threadIdx.x) * 4;
    float4 v = *(const float4*)(in + i);
    ushort4 o = {f2b(v.x), f2b(v.y), f2b(v.z), f2b(v.w)};
    *(ushort4*)(out + i) = o;
}

// ---------------------------------------------------------------------------
// transpose + cast weights: dst[n][k] = src[k][n], 512x512, bf16 out.
// ---------------------------------------------------------------------------
__global__ void transpose_w(const float* __restrict__ W1,
                            const float* __restrict__ Wv,
                            const float* __restrict__ Wo,
                            __hip_bfloat16* __restrict__ Wct,
                            __hip_bfloat16* __restrict__ Wot)
{
    __shared__ float tile[32][33];
    const float* src = blockIdx.z == 0 ? W1 : (blockIdx.z == 1 ? Wv : Wo);
    __hip_bfloat16* dst = blockIdx.z == 0 ? Wct
                        : (blockIdx.z == 1 ? Wct + 512 * 512 : Wot);
    const int r0 = blockIdx.y * 32, c0 = blockIdx.x * 32;
    const int tx = threadIdx.x, ty = threadIdx.y;
    #pragma unroll
    for (int i = 0; i < 4; ++i)
        tile[ty + 8 * i][tx] = src[(size_t)(r0 + ty + 8 * i) * 512 + c0 + tx];
    __syncthreads();
    #pragma unroll
    for (int i = 0; i < 4; ++i)
        dst[(size_t)(c0 + ty + 8 * i) * 512 + r0 + tx] =
            __float2bfloat16(tile[tx][ty + 8 * i]);
}

// ---------------------------------------------------------------------------
// bf16 MFMA GEMM: C[M,N] = A[M,512] @ Bt[N,512]^T, BM x 128 tile, 4 waves.
// MODE 0: cols<512 -> outH = bf16(tanh(.+b0)); cols>=512 -> outV = bf16(.+b1)
// MODE 1: outF = . + b0 + resid
// ---------------------------------------------------------------------------
template<int BM, int MODE>
__global__ __launch_bounds__(256) void gemm_mfma(
    const ushort_t* __restrict__ A, const ushort_t* __restrict__ Bt,
    const float* __restrict__ bias0, const float* __restrict__ bias1,
    const float* __restrict__ resid,
    __hip_bfloat16* __restrict__ outH, __hip_bfloat16* __restrict__ outV,
    float* __restrict__ outF)
{
    constexpr int WROWS = BM / 2;
    constexpr int MF    = WROWS / 16;
    constexpr int ACH   = BM / 32;
    __shared__ __align__(16) ushort_t As[BM * 64];
    __shared__ __align__(16) ushort_t Bs[128 * 64];

    const int t  = threadIdx.x;
    const int m0 = blockIdx.y * BM, n0 = blockIdx.x * 128;
    const int l  = t & 63, w = t >> 6;
    const int wr = w >> 1, wc = w & 1;
    const int l15 = l & 15, hi = l >> 4;

    const ushort_t* agp[ACH];
    const ushort_t* bgp[4];
    #pragma unroll
    for (int i = 0; i < ACH; ++i) {
        int row = (t >> 3) + 32 * i, slot = (t & 7) ^ (row & 7);
        agp[i] = A + (size_t)(m0 + row) * 512 + slot * 8;
    }
    #pragma unroll
    for (int i = 0; i < 4; ++i) {
        int row = (t >> 3) + 32 * i, slot = (t & 7) ^ (row & 7);
        bgp[i] = Bt + (size_t)(n0 + row) * 512 + slot * 8;
    }

    int aoff[MF][2], boff[4][2];
    #pragma unroll
    for (int mi = 0; mi < MF; ++mi)
        #pragma unroll
        for (int kh = 0; kh < 2; ++kh) {
            int row = wr * WROWS + mi * 16 + l15;
            aoff[mi][kh] = row * 128 + (((kh * 4 + hi) ^ (row & 7)) * 16);
        }
    #pragma unroll
    for (int nj = 0; nj < 4; ++nj)
        #pragma unroll
        for (int kh = 0; kh < 2; ++kh) {
            int row = wc * 64 + nj * 16 + l15;
            boff[nj][kh] = row * 128 + (((kh * 4 + hi) ^ (row & 7)) * 16);
        }

    f32x4 acc[MF][4];
    #pragma unroll
    for (int mi = 0; mi < MF; ++mi)
        #pragma unroll
        for (int nj = 0; nj < 4; ++nj)
            acc[mi][nj] = f32x4{0.f, 0.f, 0.f, 0.f};

    for (int k0 = 0; k0 < 512; k0 += 64) {
        __syncthreads();
        #pragma unroll
        for (int i = 0; i < ACH; ++i)
            gl_lds16(agp[i] + k0, (char*)As + (size_t)(i * 256 + t) * 16);
        #pragma unroll
        for (int i = 0; i < 4; ++i)
            gl_lds16(bgp[i] + k0, (char*)Bs + (size_t)(i * 256 + t) * 16);
        __syncthreads();
        #pragma unroll
        for (int kh = 0; kh < 2; ++kh) {
            bf16x8 af[MF], bfr[4];
            #pragma unroll
            for (int mi = 0; mi < MF; ++mi)
                af[mi] = *(const bf16x8*)((const char*)As + aoff[mi][kh]);
            #pragma unroll
            for (int nj = 0; nj < 4; ++nj)
                bfr[nj] = *(const bf16x8*)((const char*)Bs + boff[nj][kh]);
            #pragma unroll
            for (int mi = 0; mi < MF; ++mi)
                #pragma unroll
                for (int nj = 0; nj < 4; ++nj)
                    acc[mi][nj] = __builtin_amdgcn_mfma_f32_16x16x32_bf16(
                        af[mi], bfr[nj], acc[mi][nj], 0, 0, 0);
        }
    }

    #pragma unroll
    for (int nj = 0; nj < 4; ++nj) {
        const int gcol = n0 + wc * 64 + nj * 16 + l15;
        float bsv;
        if (MODE == 0) bsv = (gcol < 512) ? bias0[gcol] : bias1[gcol - 512];
        else           bsv = bias0[gcol];
        #pragma unroll
        for (int mi = 0; mi < MF; ++mi) {
            #pragma unroll
            for (int r = 0; r < 4; ++r) {
                const int grow = m0 + wr * WROWS + mi * 16 + hi * 4 + r;
                float v = acc[mi][nj][r] + bsv;
                if (MODE == 0) {
                    if (gcol < 512)
                        outH[(size_t)grow * 512 + gcol] = __float2bfloat16(tanhf(v));
                    else
                        outV[(size_t)grow * 512 + (gcol - 512)] = __float2bfloat16(v);
                } else {
                    outF[(size_t)grow * 512 + gcol] =
                        v + resid[(size_t)grow * 512 + gcol];
                }
            }
        }
    }
}

// ---------------------------------------------------------------------------
// Phase kernel: per row, 32-wide dot vs W2, then phases -> cos/sin (f32).
// ---------------------------------------------------------------------------
__global__ __launch_bounds__(256) void phase_kernel(const __hip_bfloat16* __restrict__ H,
                                                    const float* __restrict__ W2,
                                                    const float* __restrict__ b2,
                                                    const float* __restrict__ ps_p,
                                                    const float* __restrict__ cs_p,
                                                    float* __restrict__ Ca,
                                                    float* __restrict__ Sa)
{
    __shared__ __align__(16) __hip_bfloat16 Hs[8 * DD];
    const int t  = threadIdx.x;
    const int rl = t >> 5;
    const int j  = t & 31;
    const int row0 = blockIdx.x * 8;

    const float4* src = (const float4*)(H + (size_t)row0 * DD);
    float4* dst = (float4*)Hs;
    dst[t] = src[t];
    dst[t + 256] = src[t + 256];
    __syncthreads();

    float dot = 0.f;
    #pragma unroll 8
    for (int d = 0; d < DD; ++d)
        dot = fmaf(__bfloat162float(Hs[rl * DD + d]), W2[d * KK + j], dot);

    const float ps = ps_p[0];
    const float cs = cs_p[0];
    const int gr = row0 + rl;
    const int lpos = gr & (LL - 1);
    const float freq = exp2f(-(float)j * (13.287712379549449f / (float)KK));
    const float content = tanhf(dot + b2[j]) * 3.14159265358979323846f * cs;
    const float total = ps * ((float)lpos * freq) + content;
    float sv, cv;
    sincosf(total, &sv, &cv);
    Ca[(size_t)gr * KK + j] = cv;
    Sa[(size_t)gr * KK + j] = sv;
}

// ---------------------------------------------------------------------------
// Scan pass A (MFMA): per (b,ch,dh) block, PR[k][d] = sum_l C[l][k] V[l][d].
// LDS: VT [256 d][40] bf16 (V^T, pad), CT/ST [32 k][40] bf16 (C^T/S^T).
// 4 waves x 64 d, 16x16x32 MFMA, M=k(2 tiles), N=d(4 tiles), Kdim=l=32.
// ---------------------------------------------------------------------------
__global__ __launch_bounds__(256) void scanA(const __hip_bfloat16* __restrict__ Vb,
                                             const float* __restrict__ Ca,
                                             const float* __restrict__ Sa,
                                             float* __restrict__ PR,
                                             float* __restrict__ PI_)
{
    __shared__ __align__(16) ushort_t VT[256 * 40];
    __shared__ __align__(16) ushort_t CT[32 * 40];
    __shared__ __align__(16) ushort_t ST[32 * 40];
    const int t = threadIdx.x;
    const int bch = blockIdx.x, dh = blockIdx.y;
    const int b = bch >> 6, ch = bch & 63;
    const size_t vbase = ((size_t)b * LL + ch * 32) * DD + dh * 256;

    // stage V^T: thread = (lg 0..7)x(dg 0..31); 4 l-rows x 8 d each
    {
        const int lg = t >> 5, dg = t & 31;
        ushort8 r[4];
        #pragma unroll
        for (int i = 0; i < 4; ++i)
            r[i] = *(const ushort8*)((const ushort_t*)Vb + vbase
                                     + (size_t)(lg * 4 + i) * DD + dg * 8);
        #pragma unroll
        for (int jd = 0; jd < 8; ++jd) {
            ushort4 w4 = {r[0][jd], r[1][jd], r[2][jd], r[3][jd]};
            *(ushort4*)&VT[(dg * 8 + jd) * 40 + lg * 4] = w4;
        }
    }
    // stage C^T/S^T (bf16): t<64, each thread 4 k x 8 l
    if (t < 64) {
        const float* srcp = (t < 32) ? Ca : Sa;
        ushort_t* dstp = (t < 32) ? CT : ST;
        const int tt = t & 31;
        const int kg = tt >> 2, lgg = tt & 3;
        float4 v[8];
        #pragma unroll
        for (int i = 0; i < 8; ++i)
            v[i] = *(const float4*)(srcp
                    + ((size_t)b * LL + ch * 32 + lgg * 8 + i) * KK + kg * 4);
        #pragma unroll
        for (int kk2 = 0; kk2 < 4; ++kk2) {
            ushort8 w8;
            #pragma unroll
            for (int i = 0; i < 8; ++i) w8[i] = f2b(((const float*)&v[i])[kk2]);
            *(ushort8*)&dstp[(kg * 4 + kk2) * 40 + lgg * 8] = w8;
        }
    }
    __syncthreads();

    const int w = t >> 6, l = t & 63, l15 = l & 15, hi = l >> 4;
    bf16x8 afc[2], afs[2];
    #pragma unroll
    for (int mt = 0; mt < 2; ++mt) {
        afc[mt] = *(const bf16x8*)&CT[(l15 + 16 * mt) * 40 + hi * 8];
        afs[mt] = *(const bf16x8*)&ST[(l15 + 16 * mt) * 40 + hi * 8];
    }
    f32x4 aPR[2][4], aPI[2][4];
    #pragma unroll
    for (int mt = 0; mt < 2; ++mt)
        #pragma unroll
        for (int nt = 0; nt < 4; ++nt) {
            aPR[mt][nt] = f32x4{0.f,0.f,0.f,0.f};
            aPI[mt][nt] = f32x4{0.f,0.f,0.f,0.f};
        }
    #pragma unroll
    for (int nt = 0; nt < 4; ++nt) {
        bf16x8 bv = *(const bf16x8*)&VT[(w * 64 + nt * 16 + l15) * 40 + hi * 8];
        #pragma unroll
        for (int mt = 0; mt < 2; ++mt) {
            aPR[mt][nt] = __builtin_amdgcn_mfma_f32_16x16x32_bf16(afc[mt], bv, aPR[mt][nt], 0,0,0);
            aPI[mt][nt] = __builtin_amdgcn_mfma_f32_16x16x32_bf16(afs[mt], bv, aPI[mt][nt], 0,0,0);
        }
    }
    const size_t pbase = (size_t)bch * (KK * DD);
    #pragma unroll
    for (int mt = 0; mt < 2; ++mt)
        #pragma unroll
        for (int nt = 0; nt < 4; ++nt)
            #pragma unroll
            for (int r = 0; r < 4; ++r) {
                const int k = 16 * mt + hi * 4 + r;
                const int d = dh * 256 + w * 64 + nt * 16 + l15;
                PR[pbase + (size_t)k * DD + d]  = aPR[mt][nt][r];
                PI_[pbase + (size_t)k * DD + d] = aPI[mt][nt][r];
            }
}

// ---------------------------------------------------------------------------
// Scan pass B: exclusive prefix over 64 chunks, batched 16-deep loads.
// ---------------------------------------------------------------------------
__global__ __launch_bounds__(256) void scan_prefix(float* __restrict__ PR,
                                                   float* __restrict__ PI_)
{
    const int g = blockIdx.x * 256 + threadIdx.x;   // 0..32767
    const int b = g >> 14, kd = g & 16383;
    float r = 0.f, ri = 0.f;
    for (int gg = 0; gg < 4; ++gg) {
        float vr[16], vi[16];
        #pragma unroll
        for (int i = 0; i < 16; ++i) {
            size_t idx = ((size_t)(b * NCH + gg * 16 + i)) * (KK * DD) + kd;
            vr[i] = PR[idx];
            vi[i] = PI_[idx];
        }
        #pragma unroll
        for (int i = 0; i < 16; ++i) {
            size_t idx = ((size_t)(b * NCH + gg * 16 + i)) * (KK * DD) + kd;
            PR[idx] = r;  r  += vr[i];
            PI_[idx] = ri; ri += vi[i];
        }
    }
}

// ---------------------------------------------------------------------------
// Scan pass C (MFMA):
//   ret[l][d] = sum_kk [C|S][l][kk] * PPpre[kk][d]  +  sum_l' triG[l][l'] V[l'][d]
// where G = C@C^T + S@S^T masked to l'<=l (diag = K gives self term).
// Then ret *= rsqrt((gl+1)K), written bf16 in-place over Vb.
// ---------------------------------------------------------------------------
__global__ __launch_bounds__(256) void scanC(__hip_bfloat16* Vb,
                                             const float* __restrict__ Ca,
                                             const float* __restrict__ Sa,
                                             const float* __restrict__ PR,
                                             const float* __restrict__ PI_)
{
    __shared__ __align__(16) ushort_t VT[256 * 40];   // [d][l], pad->40
    __shared__ __align__(16) ushort_t PPT[256 * 72];  // [d][kk 0..63], pad->72
    __shared__ __align__(16) ushort_t CS[32 * 80];    // [l][c0..31|s0..31], pad->80
    __shared__ __align__(16) ushort_t G[32 * 40];     // [l][l'], pad->40
    __shared__ __align__(16) ushort_t RT[4][32 * 64]; // per-wave ret slab [l][d]

    const int t = threadIdx.x;
    const int bch = blockIdx.x, dh = blockIdx.y;
    const int b = bch >> 6, ch = bch & 63;
    const size_t vbase = ((size_t)b * LL + ch * 32) * DD + dh * 256;
    const size_t pbase = (size_t)bch * (KK * DD);

    // stage V^T
    {
        const int lg = t >> 5, dg = t & 31;
        ushort8 r[4];
        #pragma unroll
        for (int i = 0; i < 4; ++i)
            r[i] = *(const ushort8*)((const ushort_t*)Vb + vbase
                                     + (size_t)(lg * 4 + i) * DD + dg * 8);
        #pragma unroll
        for (int jd = 0; jd < 8; ++jd) {
            ushort4 w4 = {r[0][jd], r[1][jd], r[2][jd], r[3][jd]};
            *(ushort4*)&VT[(dg * 8 + jd) * 40 + lg * 4] = w4;
        }
    }
    // stage PP^T = [PRpre | PIpre]^T as bf16: thread = (kg 0..7)x(dg 0..31)
    {
        const int kg = t >> 5, dg = t & 31;
        float4 vR[4][2], vI[4][2];
        #pragma unroll
        for (int i = 0; i < 4; ++i) {
            const float* pr = PR + pbase + (size_t)(kg * 4 + i) * DD + dh * 256 + dg * 8;
            const float* pi = PI_ + pbase + (size_t)(kg * 4 + i) * DD + dh * 256 + dg * 8;
            vR[i][0] = *(const float4*)pr; vR[i][1] = *(const float4*)(pr + 4);
            vI[i][0] = *(const float4*)pi; vI[i][1] = *(const float4*)(pi + 4);
        }
        #pragma unroll
        for (int jd = 0; jd < 8; ++jd) {
            ushort4 wR = {f2b(((const float*)&vR[0][jd>>2])[jd&3]),
                          f2b(((const float*)&vR[1][jd>>2])[jd&3]),
                          f2b(((const float*)&vR[2][jd>>2])[jd&3]),
                          f2b(((const float*)&vR[3][jd>>2])[jd&3])};
            ushort4 wI = {f2b(((const float*)&vI[0][jd>>2])[jd&3]),
                          f2b(((const float*)&vI[1][jd>>2])[jd&3]),
                          f2b(((const float*)&vI[2][jd>>2])[jd&3]),
                          f2b(((const float*)&vI[3][jd>>2])[jd&3])};
            *(ushort4*)&PPT[(dg * 8 + jd) * 72 + kg * 4]      = wR;
            *(ushort4*)&PPT[(dg * 8 + jd) * 72 + 32 + kg * 4] = wI;
        }
    }
    // stage CS rows (no transpose): t<128 -> C, t>=128 -> S
    {
        const int half = t >> 7;            // 0: C, 1: S
        const int tt = t & 127;
        const int lrow = tt >> 2, kq = tt & 3;
        const float* srcp = half ? Sa : Ca;
        float4 v0 = *(const float4*)(srcp + ((size_t)b * LL + ch * 32 + lrow) * KK + kq * 8);
        float4 v1 = *(const float4*)(srcp + ((size_t)b * LL + ch * 32 + lrow) * KK + kq * 8 + 4);
        ushort8 w8 = {f2b(v0.x), f2b(v0.y), f2b(v0.z), f2b(v0.w),
                      f2b(v1.x), f2b(v1.y), f2b(v1.z), f2b(v1.w)};
        *(ushort8*)&CS[lrow * 80 + half * 32 + kq * 8] = w8;
    }
    __syncthreads();

    const int w = t >> 6, l = t & 63, l15 = l & 15, hi = l >> 4;

    // G = C@C^T + S@S^T, masked l'<=l, replicated per wave
    {
        bf16x8 fc[2], fs[2];
        #pragma unroll
        for (int mt = 0; mt < 2; ++mt) {
            fc[mt] = *(const bf16x8*)&CS[(l15 + 16 * mt) * 80 + hi * 8];
            fs[mt] = *(const bf16x8*)&CS[(l15 + 16 * mt) * 80 + 32 + hi * 8];
        }
        f32x4 gacc[2][2];
        #pragma unroll
        for (int mt = 0; mt < 2; ++mt)
            #pragma unroll
            for (int nt = 0; nt < 2; ++nt) {
                gacc[mt][nt] = f32x4{0.f,0.f,0.f,0.f};
                gacc[mt][nt] = __builtin_amdgcn_mfma_f32_16x16x32_bf16(fc[mt], fc[nt], gacc[mt][nt], 0,0,0);
                gacc[mt][nt] = __builtin_amdgcn_mfma_f32_16x16x32_bf16(fs[mt], fs[nt], gacc[mt][nt], 0,0,0);
            }
        #pragma unroll
        for (int mt = 0; mt < 2; ++mt)
            #pragma unroll
            for (int nt = 0; nt < 2; ++nt)
                #pragma unroll
                for (int r = 0; r < 4; ++r) {
                    const int row = 16 * mt + hi * 4 + r;
                    const int col = 16 * nt + l15;
                    float gv = (col <= row) ? gacc[mt][nt][r] : 0.f;
                    G[row * 40 + col] = f2b(gv);
                }
    }

    // main accumulation
    bf16x8 a1[2][2], ag[2];
    #pragma unroll
    for (int mt = 0; mt < 2; ++mt) {
        a1[mt][0] = *(const bf16x8*)&CS[(l15 + 16 * mt) * 80 + hi * 8];        // C
        a1[mt][1] = *(const bf16x8*)&CS[(l15 + 16 * mt) * 80 + 32 + hi * 8];   // S
        ag[mt]    = *(const bf16x8*)&G[(l15 + 16 * mt) * 40 + hi * 8];
    }
    f32x4 acc[2][4];
    #pragma unroll
    for (int mt = 0; mt < 2; ++mt)
        #pragma unroll
        for (int nt = 0; nt < 4; ++nt)
            acc[mt][nt] = f32x4{0.f,0.f,0.f,0.f};
    #pragma unroll
    for (int nt = 0; nt < 4; ++nt) {
        const int drow = w * 64 + nt * 16 + l15;
        bf16x8 bp0 = *(const bf16x8*)&PPT[drow * 72 + hi * 8];
        bf16x8 bp1 = *(const bf16x8*)&PPT[drow * 72 + 32 + hi * 8];
        bf16x8 bv  = *(const bf16x8*)&VT[drow * 40 + hi * 8];
        #pragma unroll
        for (int mt = 0; mt < 2; ++mt) {
            acc[mt][nt] = __builtin_amdgcn_mfma_f32_16x16x32_bf16(a1[mt][0], bp0, acc[mt][nt], 0,0,0);
            acc[mt][nt] = __builtin_amdgcn_mfma_f32_16x16x32_bf16(a1[mt][1], bp1, acc[mt][nt], 0,0,0);
            acc[mt][nt] = __builtin_amdgcn_mfma_f32_16x16x32_bf16(ag[mt],    bv,  acc[mt][nt], 0,0,0);
        }
    }

    // epilogue: scale, stage to per-wave LDS slab, coalesced store (in-place)
    #pragma unroll
    for (int mt = 0; mt < 2; ++mt)
        #pragma unroll
        for (int nt = 0; nt < 4; ++nt)
            #pragma unroll
            for (int r = 0; r < 4; ++r) {
                const int lrow = 16 * mt + hi * 4 + r;
                const float scale = rsqrtf((float)((ch * 32 + lrow + 1) * KK));
                RT[w][lrow * 64 + nt * 16 + l15] = f2b(acc[mt][nt][r] * scale);
            }
    // wave-local: reads wait on own LDS writes via lgkmcnt
    #pragma unroll
    for (int c = 0; c < 4; ++c) {
        const int cid = c * 64 + l;
        const int row = cid >> 3, c8 = cid & 7;
        ushort8 v = *(const ushort8*)&RT[w][row * 64 + c8 * 8];
        *(ushort8*)((ushort_t*)Vb + ((size_t)b * LL + ch * 32 + row) * DD
                    + dh * 256 + w * 64 + c8 * 8) = v;
    }
}

// ---------------------------------------------------------------------------
// LayerNorm over D=512 per row; bf16 in, bf16 out.
// ---------------------------------------------------------------------------
__global__ __launch_bounds__(256) void ln_kernel(const __hip_bfloat16* __restrict__ RET,
                                                 const float* __restrict__ g,
                                                 const float* __restrict__ be,
                                                 __hip_bfloat16* __restrict__ LN)
{
    const int row = blockIdx.x;
    const int t = threadIdx.x;
    const __hip_bfloat16* r = RET + (size_t)row * DD;
    float a = __bfloat162float(r[t]), b = __bfloat162float(r[t + 256]);
    float s = a + b, sq = fmaf(a, a, b * b);
    #pragma unroll
    for (int off = 32; off > 0; off >>= 1) {
        s  += __shfl_down(s, off);
        sq += __shfl_down(sq, off);
    }
    __shared__ float ls[4], lq[4];
    const int wid = t >> 6, lane = t & 63;
    if (lane == 0) { ls[wid] = s; lq[wid] = sq; }
    __syncthreads();
    if (t == 0) {
        ls[0] = ls[0] + ls[1] + ls[2] + ls[3];
        lq[0] = lq[0] + lq[1] + lq[2] + lq[3];
    }
    __syncthreads();
    const float mu  = ls[0] * (1.0f / DD);
    const float var = lq[0] * (1.0f / DD) - mu * mu;
    const float rstd = rsqrtf(var + 1e-5f);
    LN[(size_t)row * DD + t] =
        __float2bfloat16((a - mu) * rstd * g[t] + be[t]);
    LN[(size_t)row * DD + t + 256] =
        __float2bfloat16((b - mu) * rstd * g[t + 256] + be[t + 256]);
}

// ---------------------------------------------------------------------------
extern "C" void kernel_launch(void* const* d_in, const int* in_sizes, int n_in,
                              void* d_out, int out_size, void* d_ws, size_t ws_size,
                              hipStream_t stream)
{
    const float* x   = (const float*)d_in[0];
    const float* W1  = (const float*)d_in[1];
    const float* b1  = (const float*)d_in[2];
    const float* W2  = (const float*)d_in[3];
    const float* b2  = (const float*)d_in[4];
    const float* ps  = (const float*)d_in[5];
    const float* cs  = (const float*)d_in[6];
    const float* Wv  = (const float*)d_in[7];
    const float* bv  = (const float*)d_in[8];
    const float* lng = (const float*)d_in[9];
    const float* lnb = (const float*)d_in[10];
    const float* Wo  = (const float*)d_in[11];
    const float* bo  = (const float*)d_in[12];
    float* out = (float*)d_out;

    char* wsb = (char*)d_ws;
    __hip_bfloat16* Vb  = (__hip_bfloat16*)(wsb);                       // 4 MB
    float* PR  = (float*)(wsb + (4u  << 20));                           // 8 MB
    float* PI_ = (float*)(wsb + (12u << 20));                           // 8 MB
    float* Ca  = (float*)(wsb + (20u << 20));                           // 512 KB
    float* Sa  = (float*)(wsb + (20u << 20) + (512u << 10));            // 512 KB
    __hip_bfloat16* xb  = (__hip_bfloat16*)(wsb + (21u << 20));         // 4 MB
    __hip_bfloat16* Hb  = (__hip_bfloat16*)(wsb + (25u << 20));         // 4 MB (also LNb)
    __hip_bfloat16* Wct = (__hip_bfloat16*)(wsb + (29u << 20));         // 1 MB
    __hip_bfloat16* Wot = (__hip_bfloat16*)(wsb + (30u << 20));         // 0.5 MB

    cast_bf16<<<dim3(BL * DD / 1024), dim3(256), 0, stream>>>(x, xb);
    transpose_w<<<dim3(16, 16, 3), dim3(32, 8), 0, stream>>>(W1, Wv, Wo, Wct, Wot);
    gemm_mfma<128, 0><<<dim3(8, 32), dim3(256), 0, stream>>>(
        (const ushort_t*)xb, (const ushort_t*)Wct, b1, bv, nullptr, Hb, Vb, nullptr);
    phase_kernel<<<dim3(BL / 8), dim3(256), 0, stream>>>(Hb, W2, b2, ps, cs, Ca, Sa);
    scanA<<<dim3(BB * NCH, 2), dim3(256), 0, stream>>>(Vb, Ca, Sa, PR, PI_);
    scan_prefix<<<dim3((BB * KK * DD) / 256), dim3(256), 0, stream>>>(PR, PI_);
    scanC<<<dim3(BB * NCH, 2), dim3(256), 0, stream>>>(Vb, Ca, Sa, PR, PI_);
    ln_kernel<<<dim3(BL), dim3(256), 0, stream>>>(Vb, lng, lnb, Hb);
    gemm_mfma<64, 1><<<dim3(4, 64), dim3(256), 0, stream>>>(
        (const ushort_t*)Hb, (const ushort_t*)Wot, bo, nullptr, x, nullptr, nullptr, out);
}